// Round 1
// baseline (713.411 us; speedup 1.0000x reference)
//
#include <hip/hip_runtime.h>

// StandardAttention: fused QKV proj (bf16 MFMA GEMM) + masked softmax attention.
// B=2, N=2048, C=1024, H=16, D=64. Outputs: att [B,N,C] ++ att_weights [B,H,N,N].
//
// Round 4: staging via __builtin_amdgcn_global_load_lds (width 16) everywhere
// (LDS layouts were already linear-dest + swizzled-source, the legal pattern);
// softmax in exp2 domain (fold SCALE*log2e); mask expansion moved to the wide
// convert_in grid.
//
// ws layout (39,862,528 B):
//   [0, 25165824)         Q / K / Vt bf16 (3 x 8,388,608 B; Vt transposed [bh][d][n])
//   [25165824, 25182208)  mask int32 [b][n]
//   [25182208, 25182464)  flags (flag[0] = 1 if f32 mode, flag[1] = mask-encoding bits)
//   [25182464, 33571072)  X as bf16 [B*N][C]
//   [33571072, 39862528)  W as bf16 [3C][C]

typedef unsigned short u16;
typedef __attribute__((ext_vector_type(8))) short bf16x8;   // 8 bf16 = 4 VGPRs (MFMA A/B frag)
typedef __attribute__((ext_vector_type(4))) float f32x4;    // MFMA C/D frag

#define B_ 2
#define N_ 2048
#define H_ 16
#define D_ 64
#define QKV_MAT 4194304   /* B*H*N*D */
#define ATTW_OFF 4194304  /* B*N*C   */
#define OFF_MASK 25165824
#define OFF_FLAG 25182208
#define OFF_XB   25182464
#define OFF_WB   33571072

#define SCALE_L2 0.18033688011112042f   /* 0.125 * log2(e)  */
#define MASK_L2  -14426.950408889634f   /* -10000 * log2(e) */

__device__ __forceinline__ u16 f32_bf16(float f) {   // round-to-nearest-even
  unsigned u = __float_as_uint(f);
  u += 0x7fffu + ((u >> 16) & 1u);
  return (u16)(u >> 16);
}
__device__ __forceinline__ float bf16_f32(unsigned h) {
  return __uint_as_float(h << 16);
}
__device__ __forceinline__ bf16x8 ld_frag(const u16* p) { return *(const bf16x8*)p; }

// async global->LDS, 16B per lane. LDS dest must be wave-uniform base + lane*16
// (callers guarantee q = ro*256 + tid => contiguous per wave); global src is per-lane.
__device__ __forceinline__ void gld16(u16* l, const u16* g) {
  __builtin_amdgcn_global_load_lds(
      (const __attribute__((address_space(1))) void*)g,
      (__attribute__((address_space(3))) void*)l, 16, 0, 0);
}

// ---------------------------------------------------------------------------
// Kernel 0: detect X dtype (f32 vs bf16) + detect mask encoding.
// X vote: low u16 of each u32. bf16 data -> exponent field in [80,150] (or 0)
// essentially always; f32 data -> low u16 is mantissa garbage, ~28% hit rate.
// ---------------------------------------------------------------------------
__global__ void detect_prep(const unsigned char* __restrict__ mraw,
                            const unsigned* __restrict__ X32,
                            int* __restrict__ flag) {
  __shared__ int votes, mflags;
  const int tid = threadIdx.x;
  if (tid == 0) { votes = 0; mflags = 0; }
  __syncthreads();
  int v = 0;
  for (int i = tid; i < 4096; i += 256) {
    unsigned low = X32[i] & 0xFFFFu;
    unsigned e = (low >> 7) & 0xFFu;
    if (low == 0 || (e >= 80 && e <= 150)) v++;
  }
  atomicAdd(&votes, v);
  int fl = 0;
  for (int p = tid; p < B_ * N_; p += 256) {    // first 4096 bytes: safe in all layouts
    unsigned char c = mraw[p];
    if (c > 1) fl |= 1;                         // float-family bytes
    if (c && (p & 3) == 1) fl |= 4;             // 16-bit float layout marker
    if (c && (p & 3) != 0) fl |= 2;             // sub-4B granularity (byte bool)
    if (c && (p & 7) == 4) fl |= 8;             // 32-bit granularity (int32)
  }
  if (fl) atomicOr(&mflags, fl);
  __syncthreads();
  if (tid == 0) { flag[0] = (votes < 2600) ? 1 : 0; flag[1] = mflags; }
}

// ---------------------------------------------------------------------------
// Kernel 0b: canonical bf16 X and W in ws (RNE round if f32, copy if bf16),
// plus mask expansion to int32 (moved here from the single-block detect).
// ---------------------------------------------------------------------------
__global__ __launch_bounds__(256) void convert_in(const void* __restrict__ X,
                                                  const void* __restrict__ W,
                                                  const unsigned char* __restrict__ mraw,
                                                  u16* __restrict__ Xb, u16* __restrict__ Wb,
                                                  int* __restrict__ mout,
                                                  const int* __restrict__ flag) {
  const int f32m = flag[0];
  const int f = flag[1];
  const int gid = blockIdx.x * 256 + threadIdx.x;
  for (int i = gid; i < B_ * N_; i += gridDim.x * 256) {
    int m;
    if (f & 1) {                                 // float encodings
      if (f & 4) m = (((const u16*)mraw)[i] & 0x7FFFu) != 0;          // bf16/f16
      else       m = (((const unsigned*)mraw)[i] << 1) != 0;          // f32
    } else if (f & 2) m = mraw[i] != 0;                               // byte bool
    else if (f & 8)   m = ((const int*)mraw)[i] != 0;                 // int32
    else              m = ((const long long*)mraw)[i] != 0;           // int64
    mout[i] = m;
  }
  const int XC = (B_ * N_ * 1024) / 8;      // 524288 8-elem chunks
  const int WC = (3072 * 1024) / 8;         // 393216
  for (int idx = gid; idx < XC + WC; idx += gridDim.x * 256) {
    const void* src; u16* dst; int c;
    if (idx < XC) { c = idx; src = X; dst = Xb; }
    else          { c = idx - XC; src = W; dst = Wb; }
    if (f32m) {
      const float4* s = (const float4*)src;
      float4 a = s[c * 2], b = s[c * 2 + 1];
      unsigned p0 = (unsigned)f32_bf16(a.x) | ((unsigned)f32_bf16(a.y) << 16);
      unsigned p1 = (unsigned)f32_bf16(a.z) | ((unsigned)f32_bf16(a.w) << 16);
      unsigned p2 = (unsigned)f32_bf16(b.x) | ((unsigned)f32_bf16(b.y) << 16);
      unsigned p3 = (unsigned)f32_bf16(b.z) | ((unsigned)f32_bf16(b.w) << 16);
      ((uint4*)dst)[c] = make_uint4(p0, p1, p2, p3);
    } else {
      ((uint4*)dst)[c] = ((const uint4*)src)[c];
    }
  }
}

// ---------------------------------------------------------------------------
// Kernel 1: QKV = X @ W^T  (M=4096, N=3072, K=1024, bf16, NT layout).
// 128x128 tile, 256 threads (4 waves), BK=64. Staging via global_load_lds:
// LDS dest linear (wave-uniform base + lane*16), XOR-swizzle applied to the
// GLOBAL source chunk (m173 pattern), reads use the same swizzle.
// Epilogue scatters into Q/K [bh][n][d] and Vt [bh][d][n].
// ---------------------------------------------------------------------------
__global__ __launch_bounds__(256) void qkv_gemm(const u16* __restrict__ X,
                                                const u16* __restrict__ W,
                                                u16* __restrict__ qkv) {
  __shared__ u16 xs[128 * 64];
  __shared__ u16 wsh[128 * 64];
  const int tid = threadIdx.x;
  const int w = tid >> 6, l = tid & 63, quad = l >> 4, ln = l & 15;
  const int r0 = blockIdx.y * 128;   // rows (b*N + n)
  const int o0 = blockIdx.x * 128;   // output cols (3C)

  const f32x4 z4 = {0.f, 0.f, 0.f, 0.f};
  f32x4 acc[2][8];
#pragma unroll
  for (int rt = 0; rt < 2; rt++)
#pragma unroll
    for (int ct = 0; ct < 8; ct++) acc[rt][ct] = z4;

  for (int kc = 0; kc < 1024; kc += 64) {
#pragma unroll
    for (int ro = 0; ro < 4; ro++) {           // stage X-tile + W-tile (16KB each)
      int q = ro * 256 + tid;
      int r = q >> 3, s = q & 7;
      int c = s ^ (r & 7);                     // swizzled source chunk
      gld16(xs + q * 8, X + (size_t)(r0 + r) * 1024 + kc + c * 8);
      gld16(wsh + q * 8, W + (size_t)(o0 + r) * 1024 + kc + c * 8);
    }
    __syncthreads();
#pragma unroll
    for (int k2 = 0; k2 < 2; k2++) {           // two K=32 steps
      bf16x8 af[2], bfr[8];
#pragma unroll
      for (int rt = 0; rt < 2; rt++) {
        int row = w * 32 + rt * 16 + ln;
        int slot = (k2 * 4 + quad) ^ (row & 7);
        af[rt] = ld_frag(xs + row * 64 + slot * 8);
      }
#pragma unroll
      for (int ct = 0; ct < 8; ct++) {
        int row = ct * 16 + ln;
        int slot = (k2 * 4 + quad) ^ (row & 7);
        bfr[ct] = ld_frag(wsh + row * 64 + slot * 8);
      }
#pragma unroll
      for (int rt = 0; rt < 2; rt++)
#pragma unroll
        for (int ct = 0; ct < 8; ct++)
          acc[rt][ct] = __builtin_amdgcn_mfma_f32_16x16x32_bf16(af[rt], bfr[ct], acc[rt][ct], 0, 0, 0);
    }
    __syncthreads();
  }

  // epilogue: C/D layout col=lane&15, row=quad*4+reg
  const int b = r0 >> 11;
#pragma unroll
  for (int rt = 0; rt < 2; rt++) {
#pragma unroll
    for (int ct = 0; ct < 8; ct++) {
      int o = o0 + ct * 16 + ln;
      int sel = o >> 10;          // 0=Q 1=K 2=V (uniform within block)
      int h = (o >> 6) & 15;
      int d = o & 63;
      int nbase = (r0 & 2047) + w * 32 + rt * 16 + quad * 4;
      if (sel < 2) {
        size_t base = (size_t)sel * QKV_MAT + ((size_t)(b * 16 + h) * N_ + nbase) * D_ + d;
#pragma unroll
        for (int g = 0; g < 4; g++)
          qkv[base + (size_t)g * D_] = f32_bf16(acc[rt][ct][g]);
      } else {                    // V stored transposed [bh][d][n]; 4 consecutive n -> 8B store
        size_t base = 2 * (size_t)QKV_MAT + ((size_t)(b * 16 + h) * D_ + d) * N_ + nbase;
        unsigned lo = (unsigned)f32_bf16(acc[rt][ct][0]) | ((unsigned)f32_bf16(acc[rt][ct][1]) << 16);
        unsigned hi = (unsigned)f32_bf16(acc[rt][ct][2]) | ((unsigned)f32_bf16(acc[rt][ct][3]) << 16);
        *(uint2*)(qkv + base) = make_uint2(lo, hi);
      }
    }
  }
}

// ---------------------------------------------------------------------------
// Kernel 2: attention. One block = (b,h, 128-row Q tile), 256 threads (4 waves).
// Phase 1: l[i] via fixed-m softmax (exact: unmasked logits bounded, masked rows
// use m=MASK_L2 giving exactly P=1/N). Phase 2: recompute S^T (operand-swapped
// MFMA), P through LDS -> coalesced global write (dtype per flag), O += P*V.
// All softmax math in the exp2 domain (SCALE_L2 = 0.125*log2e folded in).
// ---------------------------------------------------------------------------
__global__ __launch_bounds__(256) void attn_kernel(const u16* __restrict__ qkv,
                                                   const int* __restrict__ mask,
                                                   void* __restrict__ outv,
                                                   const int* __restrict__ flag) {
  __shared__ u16 qs[128 * 64];   // Q tile [i][d], swizzled chunks
  __shared__ u16 ks[64 * 64];    // K tile [j][d], swizzled
  __shared__ u16 vs[64 * 64];    // Vt tile [d][j], swizzled
  __shared__ u16 ps[128 * 72];   // P tile [i][j], row stride 72 (144B, 16B-aligned)
  __shared__ float mrow[128];
  __shared__ float rlrow[128];

  const int of32 = flag[0];
  u16* outh = (u16*)outv;
  float* outf = (float*)outv;

  const int tid = threadIdx.x;
  const int w = tid >> 6, l = tid & 63, quad = l >> 4, ln = l & 15;
  const int bh = blockIdx.x & 31;        // consecutive blocks share (b,h) -> K/V L2 reuse
  const int qt = blockIdx.x >> 5;
  const int b = bh >> 4, h = bh & 15;
  const int q0 = qt * 128;

  const u16* Qg = qkv + ((size_t)bh * N_ + q0) * D_;
  const u16* Kg = qkv + QKV_MAT + (size_t)bh * N_ * D_;
  const u16* Vg = qkv + 2 * (size_t)QKV_MAT + (size_t)bh * D_ * N_;
  const int* mb = mask + b * N_;
  const size_t attw_base = (size_t)ATTW_OFF + (size_t)bh * N_ * N_ + (size_t)q0 * N_;

  // stage Q tile (16KB) async
#pragma unroll
  for (int ro = 0; ro < 4; ro++) {
    int q = ro * 256 + tid;
    int r = q >> 3, s = q & 7;
    int c = s ^ (r & 7);
    gld16(qs + q * 8, Qg + (size_t)r * D_ + c * 8);
  }
  int rowpad[2][4];
#pragma unroll
  for (int rt = 0; rt < 2; rt++)
#pragma unroll
    for (int g = 0; g < 4; g++)
      rowpad[rt][g] = mb[q0 + w * 32 + rt * 16 + quad * 4 + g];
  __syncthreads();

  // phase-1 Q A-frags (wave's 32 rows), held in regs
  bf16x8 qa[2][2];
#pragma unroll
  for (int rt = 0; rt < 2; rt++)
#pragma unroll
    for (int k2 = 0; k2 < 2; k2++) {
      int row = w * 32 + rt * 16 + ln;
      int slot = (k2 * 4 + quad) ^ (row & 7);
      qa[rt][k2] = ld_frag(qs + row * 64 + slot * 8);
    }

  float lsum[2][4] = {{0.f, 0.f, 0.f, 0.f}, {0.f, 0.f, 0.f, 0.f}};
  const f32x4 z4 = {0.f, 0.f, 0.f, 0.f};

  // ---------------- phase 1: row sums ----------------
  for (int kt = 0; kt < 32; kt++) {
#pragma unroll
    for (int ro = 0; ro < 2; ro++) {           // stage K tile (8KB) async
      int q = ro * 256 + tid;
      int r = q >> 3, s = q & 7;
      int c = s ^ (r & 7);
      gld16(ks + q * 8, Kg + (size_t)(kt * 64 + r) * D_ + c * 8);
    }
    int cp[4];
#pragma unroll
    for (int ct = 0; ct < 4; ct++) cp[ct] = mb[kt * 64 + ct * 16 + ln];
    __syncthreads();

    f32x4 sacc[2][4];
#pragma unroll
    for (int rt = 0; rt < 2; rt++)
#pragma unroll
      for (int ct = 0; ct < 4; ct++) sacc[rt][ct] = z4;
#pragma unroll
    for (int k2 = 0; k2 < 2; k2++) {
      bf16x8 kb[4];
#pragma unroll
      for (int ct = 0; ct < 4; ct++) {
        int row = ct * 16 + ln;
        int slot = (k2 * 4 + quad) ^ (row & 7);
        kb[ct] = ld_frag(ks + row * 64 + slot * 8);
      }
#pragma unroll
      for (int rt = 0; rt < 2; rt++)
#pragma unroll
        for (int ct = 0; ct < 4; ct++)
          sacc[rt][ct] = __builtin_amdgcn_mfma_f32_16x16x32_bf16(qa[rt][k2], kb[ct], sacc[rt][ct], 0, 0, 0);
    }
    __syncthreads();   // ks reads done before next iteration overwrites
#pragma unroll
    for (int rt = 0; rt < 2; rt++)
#pragma unroll
      for (int g = 0; g < 4; g++) {
        float e = 0.f;
#pragma unroll
        for (int ct = 0; ct < 4; ct++) {
          float sv = sacc[rt][ct][g] * SCALE_L2;
          sv = (rowpad[rt][g] | cp[ct]) ? MASK_L2 : sv;
          e += __builtin_amdgcn_exp2f(sv);
        }
        lsum[rt][g] += e;
      }
  }

  // reduce l across the 16 lanes of each quad-row group; publish m(log2), 1/l
#pragma unroll
  for (int rt = 0; rt < 2; rt++)
#pragma unroll
    for (int g = 0; g < 4; g++) {
      float lv = lsum[rt][g];
      lv += __shfl_xor(lv, 1);
      lv += __shfl_xor(lv, 2);
      lv += __shfl_xor(lv, 4);
      lv += __shfl_xor(lv, 8);
      if (ln == 0) {
        int i = w * 32 + rt * 16 + quad * 4 + g;
        mrow[i] = rowpad[rt][g] ? MASK_L2 : 0.f;
        rlrow[i] = rowpad[rt][g] ? (1.f / 2048.f) : (1.f / lv);
      }
    }
  __syncthreads();

  // phase-2 hoists: Q B-frags for all 128 i, plus m/1l per i-tile
  bf16x8 qb[8][2];
  float mi[8], rli[8];
#pragma unroll
  for (int it = 0; it < 8; it++) {
    int row = it * 16 + ln;
#pragma unroll
    for (int k2 = 0; k2 < 2; k2++) {
      int slot = (k2 * 4 + quad) ^ (row & 7);
      qb[it][k2] = ld_frag(qs + row * 64 + slot * 8);
    }
    mi[it] = mrow[row];
    rli[it] = rlrow[row];
  }

  f32x4 oacc[2][4];
#pragma unroll
  for (int rt = 0; rt < 2; rt++)
#pragma unroll
    for (int dt = 0; dt < 4; dt++) oacc[rt][dt] = z4;

  // ---------------- phase 2: P write + PV ----------------
  for (int kt = 0; kt < 32; kt++) {
    __syncthreads();   // B0: prior iteration's ks/vs/ps reads complete
#pragma unroll
    for (int ro = 0; ro < 2; ro++) {           // stage K (8KB) + Vt (8KB) async
      int q = ro * 256 + tid;
      int r = q >> 3, s = q & 7;
      int c = s ^ (r & 7);
      gld16(ks + q * 8, Kg + (size_t)(kt * 64 + r) * D_ + c * 8);
      gld16(vs + q * 8, Vg + (size_t)r * N_ + kt * 64 + c * 8);
    }
    int cpj[4];
#pragma unroll
    for (int g = 0; g < 4; g++) cpj[g] = mb[kt * 64 + w * 16 + quad * 4 + g];
    __syncthreads();   // B1: staging landed

    // S^T strip: wave owns 16 keys (j), all 128 i.  A=K frag, B=Q frag.
    bf16x8 ka[2];
#pragma unroll
    for (int k2 = 0; k2 < 2; k2++) {
      int row = w * 16 + ln;
      int slot = (k2 * 4 + quad) ^ (row & 7);
      ka[k2] = ld_frag(ks + row * 64 + slot * 8);
    }
#pragma unroll
    for (int it = 0; it < 8; it++) {
      f32x4 st = z4;
      st = __builtin_amdgcn_mfma_f32_16x16x32_bf16(ka[0], qb[it][0], st, 0, 0, 0);
      st = __builtin_amdgcn_mfma_f32_16x16x32_bf16(ka[1], qb[it][1], st, 0, 0, 0);
      bool rp = mi[it] < -5000.f;
      unsigned pk[4];
#pragma unroll
      for (int g = 0; g < 4; g++) {
        float sv = st[g] * SCALE_L2;
        sv = (cpj[g] || rp) ? MASK_L2 : sv;
        float p = __builtin_amdgcn_exp2f(sv - mi[it]) * rli[it];
        pk[g] = f32_bf16(p);
      }
      int iRow = it * 16 + ln;
      int jc = w * 16 + quad * 4;          // 4 consecutive j -> 8B LDS write
      *(uint2*)(ps + iRow * 72 + jc) = make_uint2(pk[0] | (pk[1] << 16), pk[2] | (pk[3] << 16));
    }
    __syncthreads();   // B2: P tile complete

    // coalesced global write of the P tile
    if (!of32) {
#pragma unroll
      for (int ro = 0; ro < 4; ro++) {
        int q = ro * 256 + tid;
        int r = q >> 3, c = q & 7;
        uint4 v = *(const uint4*)(ps + r * 72 + c * 8);
        *(uint4*)(outh + attw_base + (size_t)r * N_ + kt * 64 + c * 8) = v;
      }
    } else {
#pragma unroll
      for (int ro = 0; ro < 8; ro++) {
        int q = ro * 256 + tid;
        int r = q >> 4, c4 = q & 15;
        uint2 v = *(const uint2*)(ps + r * 72 + c4 * 4);
        float4 o = make_float4(bf16_f32(v.x & 0xFFFFu), bf16_f32(v.x >> 16),
                               bf16_f32(v.y & 0xFFFFu), bf16_f32(v.y >> 16));
        *(float4*)(outf + attw_base + (size_t)r * N_ + kt * 64 + c4 * 4) = o;
      }
    }
    // O += P * V  (A = P from LDS, B = Vt from LDS)
#pragma unroll
    for (int k2 = 0; k2 < 2; k2++) {
      bf16x8 pa[2], vb[4];
#pragma unroll
      for (int rt = 0; rt < 2; rt++) {
        int row = w * 32 + rt * 16 + ln;
        pa[rt] = ld_frag(ps + row * 72 + k2 * 32 + quad * 8);
      }
#pragma unroll
      for (int dt = 0; dt < 4; dt++) {
        int row = dt * 16 + ln;
        int slot = (k2 * 4 + quad) ^ (row & 7);
        vb[dt] = ld_frag(vs + row * 64 + slot * 8);
      }
#pragma unroll
      for (int rt = 0; rt < 2; rt++)
#pragma unroll
        for (int dt = 0; dt < 4; dt++)
          oacc[rt][dt] = __builtin_amdgcn_mfma_f32_16x16x32_bf16(pa[rt], vb[dt], oacc[rt][dt], 0, 0, 0);
    }
  }

  // att epilogue: out[b][n][h*64+d]
#pragma unroll
  for (int rt = 0; rt < 2; rt++)
#pragma unroll
    for (int dt = 0; dt < 4; dt++) {
      int d = dt * 16 + ln;
#pragma unroll
      for (int g = 0; g < 4; g++) {
        int i = w * 32 + rt * 16 + quad * 4 + g;
        size_t off = (size_t)(b * N_ + q0 + i) * 1024 + h * 64 + d;
        if (!of32) outh[off] = f32_bf16(oacc[rt][dt][g]);
        else       outf[off] = oacc[rt][dt][g];
      }
    }
}

// ---------------------------------------------------------------------------
extern "C" void kernel_launch(void* const* d_in, const int* in_sizes, int n_in,
                              void* d_out, int out_size, void* d_ws, size_t ws_size,
                              hipStream_t stream) {
  (void)in_sizes; (void)n_in; (void)out_size; (void)ws_size;
  const unsigned char* mraw = (const unsigned char*)d_in[2];
  char* ws = (char*)d_ws;
  u16* qkvws = (u16*)ws;
  int* maskws = (int*)(ws + OFF_MASK);
  int* flagws = (int*)(ws + OFF_FLAG);
  u16* Xb = (u16*)(ws + OFF_XB);
  u16* Wb = (u16*)(ws + OFF_WB);

  detect_prep<<<1, 256, 0, stream>>>(mraw, (const unsigned*)d_in[0], flagws);
  convert_in<<<1792, 256, 0, stream>>>(d_in[0], d_in[1], mraw, Xb, Wb, maskws, flagws);
  qkv_gemm<<<dim3(24, 32), 256, 0, stream>>>(Xb, Wb, qkvws);
  attn_kernel<<<512, 256, 0, stream>>>(qkvws, maskws, d_out, flagws);
}

// Round 3
// 690.415 us; speedup vs baseline: 1.0333x; 1.0333x over previous
//
#include <hip/hip_runtime.h>

// StandardAttention: fused QKV proj (bf16 MFMA GEMM) + masked softmax attention.
// B=2, N=2048, C=1024, H=16, D=64. Outputs: att [B,N,C] ++ att_weights [B,H,N,N].
//
// Round 6 == Round 5 resubmit (container infra failure, kernel audited clean):
// attn pipelined — double-buffered K/V LDS tiles, staging for kt+1 issued
// during kt's compute (vmcnt(0) drain at each barrier covered by MFMA/exp
// work), barriers 2->1 per iter (phase 1) and 3->2 (phase 2).
//
// ws layout (39,862,528 B):
//   [0, 25165824)         Q / K / Vt bf16 (3 x 8,388,608 B; Vt transposed [bh][d][n])
//   [25165824, 25182208)  mask int32 [b][n]
//   [25182208, 25182464)  flags (flag[0] = 1 if f32 mode, flag[1] = mask-encoding bits)
//   [25182464, 33571072)  X as bf16 [B*N][C]
//   [33571072, 39862528)  W as bf16 [3C][C]

typedef unsigned short u16;
typedef __attribute__((ext_vector_type(8))) short bf16x8;   // 8 bf16 = 4 VGPRs (MFMA A/B frag)
typedef __attribute__((ext_vector_type(4))) float f32x4;    // MFMA C/D frag

#define B_ 2
#define N_ 2048
#define H_ 16
#define D_ 64
#define QKV_MAT 4194304   /* B*H*N*D */
#define ATTW_OFF 4194304  /* B*N*C   */
#define OFF_MASK 25165824
#define OFF_FLAG 25182208
#define OFF_XB   25182464
#define OFF_WB   33571072

#define SCALE_L2 0.18033688011112042f   /* 0.125 * log2(e)  */
#define MASK_L2  -14426.950408889634f   /* -10000 * log2(e) */

__device__ __forceinline__ u16 f32_bf16(float f) {   // round-to-nearest-even
  unsigned u = __float_as_uint(f);
  u += 0x7fffu + ((u >> 16) & 1u);
  return (u16)(u >> 16);
}
__device__ __forceinline__ float bf16_f32(unsigned h) {
  return __uint_as_float(h << 16);
}
__device__ __forceinline__ bf16x8 ld_frag(const u16* p) { return *(const bf16x8*)p; }

// async global->LDS, 16B per lane. LDS dest must be wave-uniform base + lane*16
// (callers guarantee q = ro*256 + tid => contiguous per wave); global src is per-lane.
__device__ __forceinline__ void gld16(u16* l, const u16* g) {
  __builtin_amdgcn_global_load_lds(
      (const __attribute__((address_space(1))) void*)g,
      (__attribute__((address_space(3))) void*)l, 16, 0, 0);
}

// ---------------------------------------------------------------------------
// Kernel 0: detect X dtype (f32 vs bf16) + detect mask encoding. 1024 threads
// (single block; wider = fewer serial HBM latencies per thread).
// ---------------------------------------------------------------------------
__global__ void detect_prep(const unsigned char* __restrict__ mraw,
                            const unsigned* __restrict__ X32,
                            int* __restrict__ flag) {
  __shared__ int votes, mflags;
  const int tid = threadIdx.x;
  if (tid == 0) { votes = 0; mflags = 0; }
  __syncthreads();
  int v = 0;
  for (int i = tid; i < 4096; i += 1024) {
    unsigned low = X32[i] & 0xFFFFu;
    unsigned e = (low >> 7) & 0xFFu;
    if (low == 0 || (e >= 80 && e <= 150)) v++;
  }
  atomicAdd(&votes, v);
  int fl = 0;
  for (int p = tid; p < B_ * N_; p += 1024) {   // first 4096 bytes: safe in all layouts
    unsigned char c = mraw[p];
    if (c > 1) fl |= 1;                         // float-family bytes
    if (c && (p & 3) == 1) fl |= 4;             // 16-bit float layout marker
    if (c && (p & 3) != 0) fl |= 2;             // sub-4B granularity (byte bool)
    if (c && (p & 7) == 4) fl |= 8;             // 32-bit granularity (int32)
  }
  if (fl) atomicOr(&mflags, fl);
  __syncthreads();
  if (tid == 0) { flag[0] = (votes < 2600) ? 1 : 0; flag[1] = mflags; }
}

// ---------------------------------------------------------------------------
// Kernel 0b: canonical bf16 X and W in ws (RNE round if f32, copy if bf16),
// plus mask expansion to int32.
// ---------------------------------------------------------------------------
__global__ __launch_bounds__(256) void convert_in(const void* __restrict__ X,
                                                  const void* __restrict__ W,
                                                  const unsigned char* __restrict__ mraw,
                                                  u16* __restrict__ Xb, u16* __restrict__ Wb,
                                                  int* __restrict__ mout,
                                                  const int* __restrict__ flag) {
  const int f32m = flag[0];
  const int f = flag[1];
  const int gid = blockIdx.x * 256 + threadIdx.x;
  for (int i = gid; i < B_ * N_; i += gridDim.x * 256) {
    int m;
    if (f & 1) {                                 // float encodings
      if (f & 4) m = (((const u16*)mraw)[i] & 0x7FFFu) != 0;          // bf16/f16
      else       m = (((const unsigned*)mraw)[i] << 1) != 0;          // f32
    } else if (f & 2) m = mraw[i] != 0;                               // byte bool
    else if (f & 8)   m = ((const int*)mraw)[i] != 0;                 // int32
    else              m = ((const long long*)mraw)[i] != 0;           // int64
    mout[i] = m;
  }
  const int XC = (B_ * N_ * 1024) / 8;      // 524288 8-elem chunks
  const int WC = (3072 * 1024) / 8;         // 393216
  for (int idx = gid; idx < XC + WC; idx += gridDim.x * 256) {
    const void* src; u16* dst; int c;
    if (idx < XC) { c = idx; src = X; dst = Xb; }
    else          { c = idx - XC; src = W; dst = Wb; }
    if (f32m) {
      const float4* s = (const float4*)src;
      float4 a = s[c * 2], b = s[c * 2 + 1];
      unsigned p0 = (unsigned)f32_bf16(a.x) | ((unsigned)f32_bf16(a.y) << 16);
      unsigned p1 = (unsigned)f32_bf16(a.z) | ((unsigned)f32_bf16(a.w) << 16);
      unsigned p2 = (unsigned)f32_bf16(b.x) | ((unsigned)f32_bf16(b.y) << 16);
      unsigned p3 = (unsigned)f32_bf16(b.z) | ((unsigned)f32_bf16(b.w) << 16);
      ((uint4*)dst)[c] = make_uint4(p0, p1, p2, p3);
    } else {
      ((uint4*)dst)[c] = ((const uint4*)src)[c];
    }
  }
}

// ---------------------------------------------------------------------------
// Kernel 1: QKV = X @ W^T  (M=4096, N=3072, K=1024, bf16, NT layout).
// 128x128 tile, 256 threads (4 waves), BK=64, global_load_lds staging with
// pre-swizzled global source (m173 pattern).
// Epilogue scatters into Q/K [bh][n][d] and Vt [bh][d][n].
// ---------------------------------------------------------------------------
__global__ __launch_bounds__(256) void qkv_gemm(const u16* __restrict__ X,
                                                const u16* __restrict__ W,
                                                u16* __restrict__ qkv) {
  __shared__ u16 xs[128 * 64];
  __shared__ u16 wsh[128 * 64];
  const int tid = threadIdx.x;
  const int w = tid >> 6, l = tid & 63, quad = l >> 4, ln = l & 15;
  const int r0 = blockIdx.y * 128;   // rows (b*N + n)
  const int o0 = blockIdx.x * 128;   // output cols (3C)

  const f32x4 z4 = {0.f, 0.f, 0.f, 0.f};
  f32x4 acc[2][8];
#pragma unroll
  for (int rt = 0; rt < 2; rt++)
#pragma unroll
    for (int ct = 0; ct < 8; ct++) acc[rt][ct] = z4;

  for (int kc = 0; kc < 1024; kc += 64) {
#pragma unroll
    for (int ro = 0; ro < 4; ro++) {           // stage X-tile + W-tile (16KB each)
      int q = ro * 256 + tid;
      int r = q >> 3, s = q & 7;
      int c = s ^ (r & 7);                     // swizzled source chunk
      gld16(xs + q * 8, X + (size_t)(r0 + r) * 1024 + kc + c * 8);
      gld16(wsh + q * 8, W + (size_t)(o0 + r) * 1024 + kc + c * 8);
    }
    __syncthreads();
#pragma unroll
    for (int k2 = 0; k2 < 2; k2++) {           // two K=32 steps
      bf16x8 af[2], bfr[8];
#pragma unroll
      for (int rt = 0; rt < 2; rt++) {
        int row = w * 32 + rt * 16 + ln;
        int slot = (k2 * 4 + quad) ^ (row & 7);
        af[rt] = ld_frag(xs + row * 64 + slot * 8);
      }
#pragma unroll
      for (int ct = 0; ct < 8; ct++) {
        int row = ct * 16 + ln;
        int slot = (k2 * 4 + quad) ^ (row & 7);
        bfr[ct] = ld_frag(wsh + row * 64 + slot * 8);
      }
#pragma unroll
      for (int rt = 0; rt < 2; rt++)
#pragma unroll
        for (int ct = 0; ct < 8; ct++)
          acc[rt][ct] = __builtin_amdgcn_mfma_f32_16x16x32_bf16(af[rt], bfr[ct], acc[rt][ct], 0, 0, 0);
    }
    __syncthreads();
  }

  // epilogue: C/D layout col=lane&15, row=quad*4+reg
  const int b = r0 >> 11;
#pragma unroll
  for (int rt = 0; rt < 2; rt++) {
#pragma unroll
    for (int ct = 0; ct < 8; ct++) {
      int o = o0 + ct * 16 + ln;
      int sel = o >> 10;          // 0=Q 1=K 2=V (uniform within block)
      int h = (o >> 6) & 15;
      int d = o & 63;
      int nbase = (r0 & 2047) + w * 32 + rt * 16 + quad * 4;
      if (sel < 2) {
        size_t base = (size_t)sel * QKV_MAT + ((size_t)(b * 16 + h) * N_ + nbase) * D_ + d;
#pragma unroll
        for (int g = 0; g < 4; g++)
          qkv[base + (size_t)g * D_] = f32_bf16(acc[rt][ct][g]);
      } else {                    // V stored transposed [bh][d][n]; 4 consecutive n -> 8B store
        size_t base = 2 * (size_t)QKV_MAT + ((size_t)(b * 16 + h) * D_ + d) * N_ + nbase;
        unsigned lo = (unsigned)f32_bf16(acc[rt][ct][0]) | ((unsigned)f32_bf16(acc[rt][ct][1]) << 16);
        unsigned hi = (unsigned)f32_bf16(acc[rt][ct][2]) | ((unsigned)f32_bf16(acc[rt][ct][3]) << 16);
        *(uint2*)(qkv + base) = make_uint2(lo, hi);
      }
    }
  }
}

// ---------------------------------------------------------------------------
// Kernel 2: attention. One block = (b,h, 128-row Q tile), 256 threads (4 waves).
// Phase 1: l[i] via fixed-m softmax (exact: unmasked logits bounded, masked rows
// use m=MASK_L2 giving exactly P=1/N). Phase 2: recompute S^T (operand-swapped
// MFMA), P through LDS -> coalesced global write (dtype per flag), O += P*V.
// K/V tiles double-buffered; staging for kt+1 issued during kt's compute.
// LDS = 67 KB -> 2 blocks/CU, grid 512 = exactly 2/CU resident.
// ---------------------------------------------------------------------------
__global__ __launch_bounds__(256) void attn_kernel(const u16* __restrict__ qkv,
                                                   const int* __restrict__ mask,
                                                   void* __restrict__ outv,
                                                   const int* __restrict__ flag) {
  __shared__ u16 qs[128 * 64];      // Q tile [i][d], swizzled chunks
  __shared__ u16 ks[2][64 * 64];    // K tile [j][d], swizzled, double-buffered
  __shared__ u16 vs[2][64 * 64];    // Vt tile [d][j], swizzled, double-buffered
  __shared__ u16 ps[128 * 72];      // P tile [i][j], row stride 72 (144B, 16B-aligned)
  __shared__ float mrow[128];
  __shared__ float rlrow[128];

  const int of32 = flag[0];
  u16* outh = (u16*)outv;
  float* outf = (float*)outv;

  const int tid = threadIdx.x;
  const int w = tid >> 6, l = tid & 63, quad = l >> 4, ln = l & 15;
  const int bh = blockIdx.x & 31;        // consecutive blocks share (b,h) -> K/V L2 reuse
  const int qt = blockIdx.x >> 5;
  const int b = bh >> 4, h = bh & 15;
  const int q0 = qt * 128;

  const u16* Qg = qkv + ((size_t)bh * N_ + q0) * D_;
  const u16* Kg = qkv + QKV_MAT + (size_t)bh * N_ * D_;
  const u16* Vg = qkv + 2 * (size_t)QKV_MAT + (size_t)bh * D_ * N_;
  const int* mb = mask + b * N_;
  const size_t attw_base = (size_t)ATTW_OFF + (size_t)bh * N_ * N_ + (size_t)q0 * N_;

  // prologue: stage Q tile (16KB) + K tile kt=0 async
#pragma unroll
  for (int ro = 0; ro < 4; ro++) {
    int q = ro * 256 + tid;
    int r = q >> 3, s = q & 7;
    int c = s ^ (r & 7);
    gld16(qs + q * 8, Qg + (size_t)r * D_ + c * 8);
  }
#pragma unroll
  for (int ro = 0; ro < 2; ro++) {
    int q = ro * 256 + tid;
    int r = q >> 3, s = q & 7;
    int c = s ^ (r & 7);
    gld16(ks[0] + q * 8, Kg + (size_t)r * D_ + c * 8);
  }
  int rowpad[2][4];
#pragma unroll
  for (int rt = 0; rt < 2; rt++)
#pragma unroll
    for (int g = 0; g < 4; g++)
      rowpad[rt][g] = mb[q0 + w * 32 + rt * 16 + quad * 4 + g];
  __syncthreads();

  // phase-1 Q A-frags (wave's 32 rows), held in regs
  bf16x8 qa[2][2];
#pragma unroll
  for (int rt = 0; rt < 2; rt++)
#pragma unroll
    for (int k2 = 0; k2 < 2; k2++) {
      int row = w * 32 + rt * 16 + ln;
      int slot = (k2 * 4 + quad) ^ (row & 7);
      qa[rt][k2] = ld_frag(qs + row * 64 + slot * 8);
    }

  float lsum[2][4] = {{0.f, 0.f, 0.f, 0.f}, {0.f, 0.f, 0.f, 0.f}};
  const f32x4 z4 = {0.f, 0.f, 0.f, 0.f};

  // ---------------- phase 1: row sums (1 barrier/iter, dbuf K) ----------------
  for (int kt = 0; kt < 32; kt++) {
    const int cur = kt & 1;
    if (kt < 31) {                             // stage next K tile during compute
#pragma unroll
      for (int ro = 0; ro < 2; ro++) {
        int q = ro * 256 + tid;
        int r = q >> 3, s = q & 7;
        int c = s ^ (r & 7);
        gld16(ks[cur ^ 1] + q * 8, Kg + (size_t)((kt + 1) * 64 + r) * D_ + c * 8);
      }
    }
    int cp[4];
#pragma unroll
    for (int ct = 0; ct < 4; ct++) cp[ct] = mb[kt * 64 + ct * 16 + ln];

    f32x4 sacc[2][4];
#pragma unroll
    for (int rt = 0; rt < 2; rt++)
#pragma unroll
      for (int ct = 0; ct < 4; ct++) sacc[rt][ct] = z4;
#pragma unroll
    for (int k2 = 0; k2 < 2; k2++) {
      bf16x8 kb[4];
#pragma unroll
      for (int ct = 0; ct < 4; ct++) {
        int row = ct * 16 + ln;
        int slot = (k2 * 4 + quad) ^ (row & 7);
        kb[ct] = ld_frag(ks[cur] + row * 64 + slot * 8);
      }
#pragma unroll
      for (int rt = 0; rt < 2; rt++)
#pragma unroll
        for (int ct = 0; ct < 4; ct++)
          sacc[rt][ct] = __builtin_amdgcn_mfma_f32_16x16x32_bf16(qa[rt][k2], kb[ct], sacc[rt][ct], 0, 0, 0);
    }
#pragma unroll
    for (int rt = 0; rt < 2; rt++)
#pragma unroll
      for (int g = 0; g < 4; g++) {
        float e = 0.f;
#pragma unroll
        for (int ct = 0; ct < 4; ct++) {
          float sv = sacc[rt][ct][g] * SCALE_L2;
          sv = (rowpad[rt][g] | cp[ct]) ? MASK_L2 : sv;
          e += __builtin_amdgcn_exp2f(sv);
        }
        lsum[rt][g] += e;
      }
    __syncthreads();   // ks[cur] reads done; staging for kt+1 drained (covered above)
  }

  // issue phase-2 kt=0 K+V staging early: overlaps the softmax reduce below
#pragma unroll
  for (int ro = 0; ro < 2; ro++) {
    int q = ro * 256 + tid;
    int r = q >> 3, s = q & 7;
    int c = s ^ (r & 7);
    gld16(ks[0] + q * 8, Kg + (size_t)r * D_ + c * 8);
    gld16(vs[0] + q * 8, Vg + (size_t)r * N_ + c * 8);
  }

  // reduce l across the 16 lanes of each quad-row group; publish m(log2), 1/l
#pragma unroll
  for (int rt = 0; rt < 2; rt++)
#pragma unroll
    for (int g = 0; g < 4; g++) {
      float lv = lsum[rt][g];
      lv += __shfl_xor(lv, 1);
      lv += __shfl_xor(lv, 2);
      lv += __shfl_xor(lv, 4);
      lv += __shfl_xor(lv, 8);
      if (ln == 0) {
        int i = w * 32 + rt * 16 + quad * 4 + g;
        mrow[i] = rowpad[rt][g] ? MASK_L2 : 0.f;
        rlrow[i] = rowpad[rt][g] ? (1.f / 2048.f) : (1.f / lv);
      }
    }
  __syncthreads();   // publishes mrow/rlrow; drains kt=0 staging

  // phase-2 hoists: Q B-frags for all 128 i, plus m/1l per i-tile
  bf16x8 qb[8][2];
  float mi[8], rli[8];
#pragma unroll
  for (int it = 0; it < 8; it++) {
    int row = it * 16 + ln;
#pragma unroll
    for (int k2 = 0; k2 < 2; k2++) {
      int slot = (k2 * 4 + quad) ^ (row & 7);
      qb[it][k2] = ld_frag(qs + row * 64 + slot * 8);
    }
    mi[it] = mrow[row];
    rli[it] = rlrow[row];
  }

  f32x4 oacc[2][4];
#pragma unroll
  for (int rt = 0; rt < 2; rt++)
#pragma unroll
    for (int dt = 0; dt < 4; dt++) oacc[rt][dt] = z4;

  // ---------------- phase 2: P write + PV (2 barriers/iter, dbuf K+V) --------
  for (int kt = 0; kt < 32; kt++) {
    const int cur = kt & 1;
    int cpj[4];
#pragma unroll
    for (int g = 0; g < 4; g++) cpj[g] = mb[kt * 64 + w * 16 + quad * 4 + g];

    // S^T strip: wave owns 16 keys (j), all 128 i.  A=K frag, B=Q frag.
    bf16x8 ka[2];
#pragma unroll
    for (int k2 = 0; k2 < 2; k2++) {
      int row = w * 16 + ln;
      int slot = (k2 * 4 + quad) ^ (row & 7);
      ka[k2] = ld_frag(ks[cur] + row * 64 + slot * 8);
    }
#pragma unroll
    for (int it = 0; it < 8; it++) {
      f32x4 st = z4;
      st = __builtin_amdgcn_mfma_f32_16x16x32_bf16(ka[0], qb[it][0], st, 0, 0, 0);
      st = __builtin_amdgcn_mfma_f32_16x16x32_bf16(ka[1], qb[it][1], st, 0, 0, 0);
      bool rp = mi[it] < -5000.f;
      unsigned pk[4];
#pragma unroll
      for (int g = 0; g < 4; g++) {
        float sv = st[g] * SCALE_L2;
        sv = (cpj[g] || rp) ? MASK_L2 : sv;
        float p = __builtin_amdgcn_exp2f(sv - mi[it]) * rli[it];
        pk[g] = f32_bf16(p);
      }
      int iRow = it * 16 + ln;
      int jc = w * 16 + quad * 4;          // 4 consecutive j -> 8B LDS write
      *(uint2*)(ps + iRow * 72 + jc) = make_uint2(pk[0] | (pk[1] << 16), pk[2] | (pk[3] << 16));
    }
    __syncthreads();   // B2: P tile complete

    if (kt < 31) {     // stage next K+V during P-write + PV (drained at Bend)
#pragma unroll
      for (int ro = 0; ro < 2; ro++) {
        int q = ro * 256 + tid;
        int r = q >> 3, s = q & 7;
        int c = s ^ (r & 7);
        gld16(ks[cur ^ 1] + q * 8, Kg + (size_t)((kt + 1) * 64 + r) * D_ + c * 8);
        gld16(vs[cur ^ 1] + q * 8, Vg + (size_t)r * N_ + (kt + 1) * 64 + c * 8);
      }
    }

    // coalesced global write of the P tile
    if (!of32) {
#pragma unroll
      for (int ro = 0; ro < 4; ro++) {
        int q = ro * 256 + tid;
        int r = q >> 3, c = q & 7;
        uint4 v = *(const uint4*)(ps + r * 72 + c * 8);
        *(uint4*)(outh + attw_base + (size_t)r * N_ + kt * 64 + c * 8) = v;
      }
    } else {
#pragma unroll
      for (int ro = 0; ro < 8; ro++) {
        int q = ro * 256 + tid;
        int r = q >> 4, c4 = q & 15;
        uint2 v = *(const uint2*)(ps + r * 72 + c4 * 4);
        float4 o = make_float4(bf16_f32(v.x & 0xFFFFu), bf16_f32(v.x >> 16),
                               bf16_f32(v.y & 0xFFFFu), bf16_f32(v.y >> 16));
        *(float4*)(outf + attw_base + (size_t)r * N_ + kt * 64 + c4 * 4) = o;
      }
    }
    // O += P * V  (A = P from LDS, B = Vt from LDS)
#pragma unroll
    for (int k2 = 0; k2 < 2; k2++) {
      bf16x8 pa[2], vb[4];
#pragma unroll
      for (int rt = 0; rt < 2; rt++) {
        int row = w * 32 + rt * 16 + ln;
        pa[rt] = ld_frag(ps + row * 72 + k2 * 32 + quad * 8);
      }
#pragma unroll
      for (int dt = 0; dt < 4; dt++) {
        int row = dt * 16 + ln;
        int slot = (k2 * 4 + quad) ^ (row & 7);
        vb[dt] = ld_frag(vs[cur] + row * 64 + slot * 8);
      }
#pragma unroll
      for (int rt = 0; rt < 2; rt++)
#pragma unroll
        for (int dt = 0; dt < 4; dt++)
          oacc[rt][dt] = __builtin_amdgcn_mfma_f32_16x16x32_bf16(pa[rt], vb[dt], oacc[rt][dt], 0, 0, 0);
    }
    __syncthreads();   // Bend: ps/vs[cur] reads done; next-iter staging drained
  }

  // att epilogue: out[b][n][h*64+d]
#pragma unroll
  for (int rt = 0; rt < 2; rt++)
#pragma unroll
    for (int dt = 0; dt < 4; dt++) {
      int d = dt * 16 + ln;
#pragma unroll
      for (int g = 0; g < 4; g++) {
        int i = w * 32 + rt * 16 + quad * 4 + g;
        size_t off = (size_t)(b * N_ + q0 + i) * 1024 + h * 64 + d;
        if (!of32) outh[off] = f32_bf16(oacc[rt][dt][g]);
        else       outf[off] = oacc[rt][dt][g];
      }
    }
}

// ---------------------------------------------------------------------------
extern "C" void kernel_launch(void* const* d_in, const int* in_sizes, int n_in,
                              void* d_out, int out_size, void* d_ws, size_t ws_size,
                              hipStream_t stream) {
  (void)in_sizes; (void)n_in; (void)out_size; (void)ws_size;
  const unsigned char* mraw = (const unsigned char*)d_in[2];
  char* ws = (char*)d_ws;
  u16* qkvws = (u16*)ws;
  int* maskws = (int*)(ws + OFF_MASK);
  int* flagws = (int*)(ws + OFF_FLAG);
  u16* Xb = (u16*)(ws + OFF_XB);
  u16* Wb = (u16*)(ws + OFF_WB);

  detect_prep<<<1, 1024, 0, stream>>>(mraw, (const unsigned*)d_in[0], flagws);
  convert_in<<<1792, 256, 0, stream>>>(d_in[0], d_in[1], mraw, Xb, Wb, maskws, flagws);
  qkv_gemm<<<dim3(24, 32), 256, 0, stream>>>(Xb, Wb, qkvws);
  attn_kernel<<<512, 256, 0, stream>>>(qkvws, maskws, d_out, flagws);
}